// Round 6
// baseline (1324.848 us; speedup 1.0000x reference)
//
#include <hip/hip_runtime.h>
#include <cstdint>
#include <cstddef>

typedef unsigned short u16;
typedef __attribute__((ext_vector_type(8))) short short8;   // 8 x bf16 (4 VGPRs) MFMA A/B frag
typedef __attribute__((ext_vector_type(4))) float f32x4;    // MFMA C/D frag

#define NTOK 65536
#define HID 512
#define NVOCAB 1024

// ---------- bf16 helpers (raw-bit, RNE) ----------
__device__ __forceinline__ u16 f2bf(float f) {
  union { float f; uint32_t u; } v; v.f = f;
  uint32_t r = (v.u + 0x7FFFu + ((v.u >> 16) & 1u)) >> 16;
  return (u16)r;
}
__device__ __forceinline__ float bf2f(u16 b) {
  union { uint32_t u; float f; } v; v.u = ((uint32_t)b) << 16;
  return v.f;
}

// ---------- hash constants (precomputed from reference) ----------
__constant__ uint32_t P24[24] = {
  2654435761u, 2246822519u, 3266489917u, 2028178513u, 1220703125u,
  1610612741u, 805306457u, 402653189u, 3674653429u, 2860486313u,
  1073676287u, 2971215073u, 1500450271u, 3267000013u, 2654435789u,
  4049292737u, 2246822531u, 3266489927u, 2028178519u, 1220703133u,
  1610612743u, 805306459u, 402653191u, 3674653433u};
__constant__ unsigned char OFFS[32][3] = {
  {1,0,0},{2,0,0},{3,0,0},{4,0,0},{5,0,0},{6,0,0},{7,0,0},{8,0,0},
  {1,2,0},{2,3,0},{3,4,0},{1,3,0},{2,4,0},{1,4,0},{1,5,0},{2,5,0},
  {3,5,0},{1,6,0},{2,6,0},{1,7,0},
  {1,2,3},{1,2,4},{1,3,5},{2,3,4},{1,2,5},{1,3,4},{2,4,6},{1,4,7},
  {1,8,0},{1,9,0},{1,10,0},{1,11,0}};
__constant__ unsigned char PLEN[32] = {
  1,1,1,1,1,1,1,1, 2,2,2,2,2,2,2,2,2,2,2,2, 3,3,3,3,3,3,3,3, 2,2,2,2};

// ---------- weight repack for 16-wave geometry ----------
// dst 16B chunk c within a layer: lane=c&63, ni=(c>>6)&1, kk=(c>>7)&15,
// w=c>>11 (0..15). Source element block: row = w*32 + ni*16 + (lane&15),
// col = kk*32 + (lane>>4)*8 .. +8. A wave's Wf load reads 1024 CONTIGUOUS
// bytes (base + lane*16) — perfectly coalesced sequential L2 stream.
__global__ __launch_bounds__(256) void pack_w(
    const float* __restrict__ w_in, const float* __restrict__ mlp_ws,
    const float* __restrict__ w_out, u16* __restrict__ Wp)
{
  const int gid  = blockIdx.x * 256 + threadIdx.x;   // 0..196607
  const int L    = gid >> 15;                        // layer 0..5
  const int c    = gid & 32767;
  const int lane = c & 63;
  const int ni   = (c >> 6) & 1;
  const int kk   = (c >> 7) & 15;
  const int w    = c >> 11;                          // 0..15
  const float* base =
      (L == 0) ? w_in :
      (L <= 3) ? mlp_ws + (size_t)(L - 1) * 262144 :
                 w_out  + (size_t)(L - 4) * 262144;
  const int row = (w << 5) + (ni << 4) + (lane & 15);
  const int col = (kk << 5) + ((lane >> 4) << 3);
  const float* s = base + (size_t)row * 512 + col;
  float4 f0 = ((const float4*)s)[0];
  float4 f1 = ((const float4*)s)[1];
  short8 o;
  o[0]=(short)f2bf(f0.x); o[1]=(short)f2bf(f0.y); o[2]=(short)f2bf(f0.z); o[3]=(short)f2bf(f0.w);
  o[4]=(short)f2bf(f1.x); o[5]=(short)f2bf(f1.y); o[6]=(short)f2bf(f1.z); o[7]=(short)f2bf(f1.w);
  *(short8*)(Wp + (size_t)gid * 8) = o;
}

// ---------- fully fused, software-pipelined persistent blocks ----------
// Grid = 256 (1 block/CU), 1024 threads = 16 waves (4/SIMD). Each block
// processes 4 token-tiles of 64 sequentially with DOUBLE-BUFFERED h
// (2 x 64 KB LDS): while tile j's logits layers (gemm4/5, read-only on h)
// run, tile j+1's features are gathered (issue early / consume late, T14)
// and written into the other buffer — the ~90 µs chip-wide feature phase
// hides under MFMA instead of exposing the matrix pipe.
// Wave w owns W-rows [w*32,(w+1)*32) (ni=0..1), tokens ti=0..3: acc 2x4.
// h swizzle: 16B-chunk index ^= (t&7) at feature write, epilogue write,
// and fragment read (involution, verified R4/R5).
__global__ __launch_bounds__(1024, 4)
void fused_all(const int* __restrict__ chars, const float* __restrict__ byte_embed,
               const float* __restrict__ hash_tables, const u16* __restrict__ Wp,
               const float* __restrict__ bIn, const float* __restrict__ bMlp,
               const float* __restrict__ bOut, float* __restrict__ out)
{
  __shared__ __align__(16) u16 hh[2][64 * 512];   // 2 x 64 KiB
  const int tid  = threadIdx.x;
  const int w    = tid >> 6;        // wave 0..15 : W-row block of 32
  const int lane = tid & 63;
  const int g    = lane >> 4;       // k-chunk group / D-row group
  const int lr   = lane & 15;       // A: W-row ; B/D: token
  const int swz  = (lr & 7) << 3;   // elem-XOR mask (16B granule) for h rows
  const int sub  = tid & 31;        // feat: table id / byte-chunk id
  const int tl   = tid >> 5;        // feat: token-local 0..31
  const int pl   = (int)PLEN[sub];

  f32x4 acc[2][4];
  float4 G0, G1, G2, G3, G4, G5;    // staged feature gathers (issue->consume)
  float  frS;

  // ---- feature pass p (tokens p*32+tl) of tile at tok0t: issue gathers ----
  auto feat_issue = [&](size_t tok0t, int p) {
    const int tr = (p << 5) + tl;
    const size_t t = tok0t + tr;
    const int pos = (int)(t & 2047);          // position within sequence
    const int c = chars[t];
    long long hv = 0;
    #pragma unroll
    for (int k = 0; k < 3; ++k) {
      if (k < pl) {
        const int off = (int)OFFS[sub][k];
        const long long tok = (pos >= off) ? (long long)chars[t - off] : 0ll;
        hv ^= tok * (long long)P24[(3 * sub + k) % 24];  // tok<2^10, prime<2^32: no ovf
      }
    }
    const int idx_lo = (int)(hv & 4095);      // hv >= 0
    const long long sp = (long long)P24[(3 * sub + pl) % 24];
    // int64 wrap-around multiply (matches jax int64), arithmetic >>16
    const long long prod = (long long)((unsigned long long)hv * (unsigned long long)sp);
    const int idx_hi = (int)((hv ^ (prod >> 16)) & 4095);
    frS = ((float)(int)((hv >> 3) & 255) / 255.0f) * 0.4f;
    const float* plo = hash_tables + (((size_t)sub << 12) + (size_t)idx_lo) * 8;
    const float* phi = hash_tables + (((size_t)sub << 12) + (size_t)idx_hi) * 8;
    const float* pby = byte_embed + ((size_t)c << 8) + (sub << 3);
    G0 = ((const float4*)plo)[0]; G1 = ((const float4*)plo)[1];
    G2 = ((const float4*)phi)[0]; G3 = ((const float4*)phi)[1];
    G4 = ((const float4*)pby)[0]; G5 = ((const float4*)pby)[1];
  };
  // ---- finish pass p: interpolate + bf16 + swizzled LDS write ----
  auto feat_consume = [&](u16* hb, int p) {
    const int tr = (p << 5) + tl;
    const int sw = (tr & 7) << 3;
    short8 ob;
    ob[0]=(short)f2bf(G4.x); ob[1]=(short)f2bf(G4.y); ob[2]=(short)f2bf(G4.z); ob[3]=(short)f2bf(G4.w);
    ob[4]=(short)f2bf(G5.x); ob[5]=(short)f2bf(G5.y); ob[6]=(short)f2bf(G5.z); ob[7]=(short)f2bf(G5.w);
    *(short8*)&hb[(tr << 9) + ((sub << 3) ^ sw)] = ob;
    const float fr = frS, om = 1.0f - fr;
    short8 oh;
    oh[0]=(short)f2bf(G0.x*om + G2.x*fr); oh[1]=(short)f2bf(G0.y*om + G2.y*fr);
    oh[2]=(short)f2bf(G0.z*om + G2.z*fr); oh[3]=(short)f2bf(G0.w*om + G2.w*fr);
    oh[4]=(short)f2bf(G1.x*om + G3.x*fr); oh[5]=(short)f2bf(G1.y*om + G3.y*fr);
    oh[6]=(short)f2bf(G1.z*om + G3.z*fr); oh[7]=(short)f2bf(G1.w*om + G3.w*fr);
    *(short8*)&hb[(tr << 9) + ((256 + (sub << 3)) ^ sw)] = oh;
  };

  // GEMM: acc[ni][ti] += Wp rows [w*32+ni*16..] x h-tokens [ti*16..],
  // K-chunks [kk0,kk1). W from packed global (coalesced), h from LDS.
  auto gemm = [&](int L, const u16* hb, int kk0, int kk1, bool zero) {
    if (zero) {
      #pragma unroll
      for (int ni = 0; ni < 2; ++ni)
        #pragma unroll
        for (int ti = 0; ti < 4; ++ti) acc[ni][ti] = (f32x4){0.f, 0.f, 0.f, 0.f};
    }
    const u16* Wl = Wp + (size_t)L * 262144 + (w << 14) + (lane << 3);
    #pragma unroll
    for (int kk = kk0; kk < kk1; ++kk) {
      short8 Wf[2], hf[4];
      Wf[0] = *(const short8*)(Wl + (kk << 10));
      Wf[1] = *(const short8*)(Wl + (kk << 10) + 512);
      const int kb = ((kk << 5) + (g << 3)) ^ swz;
      #pragma unroll
      for (int ti = 0; ti < 4; ++ti)
        hf[ti] = *(const short8*)&hb[(((ti << 4) + lr) << 9) + kb];
      __builtin_amdgcn_s_setprio(1);
      #pragma unroll
      for (int ni = 0; ni < 2; ++ni)
        #pragma unroll
        for (int ti = 0; ti < 4; ++ti)
          acc[ni][ti] = __builtin_amdgcn_mfma_f32_16x16x32_bf16(Wf[ni], hf[ti], acc[ni][ti], 0, 0, 0);
      __builtin_amdgcn_s_setprio(0);
    }
  };

  // hidden-layer epilogue: h[t][n] = relu(acc + b) (+ h_old), in place
  auto epi_h = [&](const float* __restrict__ bias, bool resid, u16* hb) {
    __syncthreads();                     // all GEMM reads of hb done blockwide
    #pragma unroll
    for (int ni = 0; ni < 2; ++ni) {
      const int nb = (w << 5) + (ni << 4) + (g << 2);
      const float4 b4 = *(const float4*)(bias + nb);
      #pragma unroll
      for (int ti = 0; ti < 4; ++ti) {
        const int t = (ti << 4) + lr;
        u16* pp = &hb[(t << 9) + (nb ^ swz)];
        float v0 = fmaxf(acc[ni][ti][0] + b4.x, 0.f);
        float v1 = fmaxf(acc[ni][ti][1] + b4.y, 0.f);
        float v2 = fmaxf(acc[ni][ti][2] + b4.z, 0.f);
        float v3 = fmaxf(acc[ni][ti][3] + b4.w, 0.f);
        if (resid) {                     // lane-private 8B: safe in-place
          const uint2 r2 = *(const uint2*)pp;
          v0 += bf2f((u16)(r2.x & 0xffffu)); v1 += bf2f((u16)(r2.x >> 16));
          v2 += bf2f((u16)(r2.y & 0xffffu)); v3 += bf2f((u16)(r2.y >> 16));
        }
        uint2 o;
        o.x = (uint32_t)f2bf(v0) | ((uint32_t)f2bf(v1) << 16);
        o.y = (uint32_t)f2bf(v2) | ((uint32_t)f2bf(v3) << 16);
        *(uint2*)pp = o;
      }
    }
    __syncthreads();
  };

  // output epilogue: coalesced float4 logits store
  auto epi_out = [&](const float* __restrict__ bias, int vb, size_t tok0t) {
    #pragma unroll
    for (int ni = 0; ni < 2; ++ni) {
      const int nb = (w << 5) + (ni << 4) + (g << 2);
      const float4 b4 = *(const float4*)(bias + nb);
      #pragma unroll
      for (int ti = 0; ti < 4; ++ti) {
        const int t = (ti << 4) + lr;
        float4 o;
        o.x = acc[ni][ti][0] + b4.x;
        o.y = acc[ni][ti][1] + b4.y;
        o.z = acc[ni][ti][2] + b4.z;
        o.w = acc[ni][ti][3] + b4.w;
        *(float4*)(out + (tok0t + t) * NVOCAB + vb + nb) = o;
      }
    }
  };

  const size_t base = (size_t)blockIdx.x << 8;   // 4 tiles x 64 tokens

  // prologue: features of tile 0 into hh[0] (latency exposed once per block)
  feat_issue(base, 0); feat_consume(hh[0], 0);
  feat_issue(base, 1); feat_consume(hh[0], 1);
  __syncthreads();

  #pragma unroll 1
  for (int j = 0; j < 4; ++j) {
    u16* hc = hh[j & 1];
    u16* hn = hh[(j & 1) ^ 1];
    const size_t tk0 = base + ((size_t)j << 6);
    const bool more = (j < 3);

    // layer 0 + residual blocks (h round-trips in LDS)
    gemm(0, hc, 0, 16, true);  epi_h(bIn,         false, hc);
    gemm(1, hc, 0, 16, true);  epi_h(bMlp,        true,  hc);
    gemm(2, hc, 0, 16, true);  epi_h(bMlp + 512,  true,  hc);
    gemm(3, hc, 0, 16, true);  epi_h(bMlp + 1024, true,  hc);

    if (more) {
      // logits layers interleaved with next tile's feature pipeline.
      // hn is free: its last reads were tile j-1's gemm(5), fenced by the
      // end-of-tile barrier. Writes to hn race nothing (hc reads only).
      gemm(4, hc, 0, 8, true);
      feat_issue(tk0 + 64, 0);           // gathers hide under gemm4b
      gemm(4, hc, 8, 16, false);
      feat_consume(hn, 0);
      feat_issue(tk0 + 64, 1);           // gathers hide under stores+gemm5a
      epi_out(bOut, 0, tk0);
      gemm(5, hc, 0, 8, true);
      feat_consume(hn, 1);
      gemm(5, hc, 8, 16, false);
      epi_out(bOut + 512, 512, tk0);
      __syncthreads();                   // hn visible before next tile's gemm0
    } else {
      gemm(4, hc, 0, 16, true);  epi_out(bOut,       0,   tk0);
      gemm(5, hc, 0, 16, true);  epi_out(bOut + 512, 512, tk0);
    }
  }
}

extern "C" void kernel_launch(void* const* d_in, const int* in_sizes, int n_in,
                              void* d_out, int out_size, void* d_ws, size_t ws_size,
                              hipStream_t stream) {
  const int*   chars      = (const int*)  d_in[0];
  const float* byte_embed = (const float*)d_in[1];
  const float* hash_tabs  = (const float*)d_in[2];
  const float* w_in       = (const float*)d_in[3];
  const float* b_in       = (const float*)d_in[4];
  const float* mlp_ws     = (const float*)d_in[5];
  const float* mlp_bs     = (const float*)d_in[6];
  const float* w_out      = (const float*)d_in[7];
  const float* b_out      = (const float*)d_in[8];

  // ws: packed weights, 6 layers x 512KB bf16 = 3 MB
  u16* Wp = (u16*)d_ws;

  pack_w<<<dim3(768), dim3(256), 0, stream>>>(w_in, mlp_ws, w_out, Wp);

  fused_all<<<dim3(256), dim3(1024), 0, stream>>>(
      chars, byte_embed, hash_tabs, Wp, b_in, mlp_bs, b_out, (float*)d_out);
}

// Round 8
// 484.121 us; speedup vs baseline: 2.7366x; 2.7366x over previous
//
#include <hip/hip_runtime.h>
#include <cstdint>
#include <cstddef>

typedef unsigned short u16;
typedef __attribute__((ext_vector_type(8))) short short8;   // 8 x bf16 (4 VGPRs) MFMA A/B frag
typedef __attribute__((ext_vector_type(4))) float f32x4;    // MFMA C/D frag / nt-store vec

#define NTOK 65536
#define HID 512
#define NVOCAB 1024

// ---------- bf16 helpers (raw-bit, RNE) ----------
__device__ __forceinline__ u16 f2bf(float f) {
  union { float f; uint32_t u; } v; v.f = f;
  uint32_t r = (v.u + 0x7FFFu + ((v.u >> 16) & 1u)) >> 16;
  return (u16)r;
}
__device__ __forceinline__ float bf2f(u16 b) {
  union { uint32_t u; float f; } v; v.u = ((uint32_t)b) << 16;
  return v.f;
}

// ---------- hash constants (precomputed from reference) ----------
__constant__ uint32_t P24[24] = {
  2654435761u, 2246822519u, 3266489917u, 2028178513u, 1220703125u,
  1610612741u, 805306457u, 402653189u, 3674653429u, 2860486313u,
  1073676287u, 2971215073u, 1500450271u, 3267000013u, 2654435789u,
  4049292737u, 2246822531u, 3266489927u, 2028178519u, 1220703133u,
  1610612743u, 805306459u, 402653191u, 3674653433u};
__constant__ unsigned char OFFS[32][3] = {
  {1,0,0},{2,0,0},{3,0,0},{4,0,0},{5,0,0},{6,0,0},{7,0,0},{8,0,0},
  {1,2,0},{2,3,0},{3,4,0},{1,3,0},{2,4,0},{1,4,0},{1,5,0},{2,5,0},
  {3,5,0},{1,6,0},{2,6,0},{1,7,0},
  {1,2,3},{1,2,4},{1,3,5},{2,3,4},{1,2,5},{1,3,4},{2,4,6},{1,4,7},
  {1,8,0},{1,9,0},{1,10,0},{1,11,0}};
__constant__ unsigned char PLEN[32] = {
  1,1,1,1,1,1,1,1, 2,2,2,2,2,2,2,2,2,2,2,2, 3,3,3,3,3,3,3,3, 2,2,2,2};

// ---------- weight repack (8-wave geometry, as verified in R4/R5) ----------
// dst 16B chunk c within layer: lane=c&63, ni=(c>>6)&3, kk=(c>>8)&15,
// w=c>>12. Source element block: row = w*64+ni*16+(lane&15),
// col = kk*32+(lane>>4)*8 .. +8. A wave's Wf load then reads 1024 CONTIGUOUS
// bytes (base + lane*16) — perfectly coalesced sequential L2 stream.
__global__ __launch_bounds__(256) void pack_w(
    const float* __restrict__ w_in, const float* __restrict__ mlp_ws,
    const float* __restrict__ w_out, u16* __restrict__ Wp)
{
  const int gid  = blockIdx.x * 256 + threadIdx.x;   // 0..196607
  const int L    = gid >> 15;                        // layer 0..5
  const int c    = gid & 32767;
  const int lane = c & 63;
  const int ni   = (c >> 6) & 3;
  const int kk   = (c >> 8) & 15;
  const int w    = c >> 12;
  const float* base =
      (L == 0) ? w_in :
      (L <= 3) ? mlp_ws + (size_t)(L - 1) * 262144 :
                 w_out  + (size_t)(L - 4) * 262144;
  const int row = (w << 6) + (ni << 4) + (lane & 15);
  const int col = (kk << 5) + ((lane >> 4) << 3);
  const float* s = base + (size_t)row * 512 + col;
  float4 f0 = ((const float4*)s)[0];
  float4 f1 = ((const float4*)s)[1];
  short8 o;
  o[0]=(short)f2bf(f0.x); o[1]=(short)f2bf(f0.y); o[2]=(short)f2bf(f0.z); o[3]=(short)f2bf(f0.w);
  o[4]=(short)f2bf(f1.x); o[5]=(short)f2bf(f1.y); o[6]=(short)f2bf(f1.z); o[7]=(short)f2bf(f1.w);
  *(short8*)(Wp + (size_t)gid * 8) = o;
}

// ---------- fully fused: features + all 5 layers, h resident in LDS ----------
// R5 geometry (verified best): block = 64 tokens, 8 waves (512 thr),
// LDS h[64][512] bf16 = 64 KB -> 2 blocks/CU, grid = 1024 (one tile/block,
// short in-phase blocks keep the W stream L2-coherent across blocks).
// R7/R8 changes vs R5:
//  (1) feature phase is a 2-deep NAMED software pipeline (issue pass p+1's
//      12 gathers before consuming pass p) -> ~12 loads in flight per thread
//      instead of 6 with a full drain per pass; latency-bound -> BW-bound.
//      No gather state is ever live across a GEMM (the R6 spill lesson).
//  (2) logits stores are non-temporal (via ext_vector f32x4 — HIP float4 is
//      rejected by the builtin): 268 MB of streaming writes no longer evict
//      the hash tables / W stream from the 4 MB/XCD L2.
__global__ __launch_bounds__(512, 4)
void fused_all(const int* __restrict__ chars, const float* __restrict__ byte_embed,
               const float* __restrict__ hash_tables, const u16* __restrict__ Wp,
               const float* __restrict__ bIn, const float* __restrict__ bMlp,
               const float* __restrict__ bOut, float* __restrict__ out)
{
  __shared__ __align__(16) u16 hbuf[64 * 512];   // 64 KiB
  const int tid  = threadIdx.x;
  const int w    = tid >> 6;        // wave 0..7 : W-row block of 64
  const int lane = tid & 63;
  const int g    = lane >> 4;       // k-chunk group / D-row group
  const int lr   = lane & 15;       // A: W-row ; B/D: token
  const size_t tok0 = (size_t)blockIdx.x << 6;
  const int swz = (lr & 7) << 3;    // elem-XOR mask (16B granule) for h rows

  // ================= feature phase: 2-deep pipelined gathers ================
  {
    const int sub = tid & 31;       // table id / byte-chunk id
    const int tl  = tid >> 5;       // token-local 0..15
    const int pl  = (int)PLEN[sub];

    // issue: compute hash for token row tr, start all 6 16B gathers
    auto issue = [&](int tr, float4& g0, float4& g1, float4& g2,
                     float4& g3, float4& g4, float4& g5, float& fr) {
      const size_t t = tok0 + tr;
      const int pos = (int)(t & 2047);         // position within sequence
      const int c = chars[t];
      long long hv = 0;
      #pragma unroll
      for (int k = 0; k < 3; ++k) {
        if (k < pl) {
          const int off = (int)OFFS[sub][k];
          const long long tok = (pos >= off) ? (long long)chars[t - off] : 0ll;
          hv ^= tok * (long long)P24[(3 * sub + k) % 24]; // tok<2^10, prime<2^32: no ovf
        }
      }
      const int idx_lo = (int)(hv & 4095);     // hv >= 0
      const long long sp = (long long)P24[(3 * sub + pl) % 24];
      // int64 wrap-around multiply (matches jax int64), arithmetic >>16
      const long long prod = (long long)((unsigned long long)hv * (unsigned long long)sp);
      const int idx_hi = (int)((hv ^ (prod >> 16)) & 4095);
      fr = ((float)(int)((hv >> 3) & 255) / 255.0f) * 0.4f;
      const float* plo = hash_tables + (((size_t)sub << 12) + (size_t)idx_lo) * 8;
      const float* phi = hash_tables + (((size_t)sub << 12) + (size_t)idx_hi) * 8;
      const float* pby = byte_embed + ((size_t)c << 8) + (sub << 3);
      g0 = ((const float4*)plo)[0]; g1 = ((const float4*)plo)[1];
      g2 = ((const float4*)phi)[0]; g3 = ((const float4*)phi)[1];
      g4 = ((const float4*)pby)[0]; g5 = ((const float4*)pby)[1];
    };
    // consume: interpolate + bf16 + swizzled LDS write for token row tr
    auto consume = [&](int tr, float4 g0, float4 g1, float4 g2,
                       float4 g3, float4 g4, float4 g5, float fr) {
      const int sw = (tr & 7) << 3;
      short8 ob;
      ob[0]=(short)f2bf(g4.x); ob[1]=(short)f2bf(g4.y); ob[2]=(short)f2bf(g4.z); ob[3]=(short)f2bf(g4.w);
      ob[4]=(short)f2bf(g5.x); ob[5]=(short)f2bf(g5.y); ob[6]=(short)f2bf(g5.z); ob[7]=(short)f2bf(g5.w);
      *(short8*)&hbuf[(tr << 9) + ((sub << 3) ^ sw)] = ob;
      const float om = 1.0f - fr;
      short8 oh;
      oh[0]=(short)f2bf(g0.x*om + g2.x*fr); oh[1]=(short)f2bf(g0.y*om + g2.y*fr);
      oh[2]=(short)f2bf(g0.z*om + g2.z*fr); oh[3]=(short)f2bf(g0.w*om + g2.w*fr);
      oh[4]=(short)f2bf(g1.x*om + g3.x*fr); oh[5]=(short)f2bf(g1.y*om + g3.y*fr);
      oh[6]=(short)f2bf(g1.z*om + g3.z*fr); oh[7]=(short)f2bf(g1.w*om + g3.w*fr);
      *(short8*)&hbuf[(tr << 9) + ((256 + (sub << 3)) ^ sw)] = oh;
    };

    float4 A0, A1, A2, A3, A4, A5; float frA;   // named 2-deep pipeline state
    float4 B0, B1, B2, B3, B4, B5; float frB;   // (rule #20: no runtime idx)
    issue(tl,      A0, A1, A2, A3, A4, A5, frA);
    issue(16 + tl, B0, B1, B2, B3, B4, B5, frB);
    consume(tl,      A0, A1, A2, A3, A4, A5, frA);
    issue(32 + tl,   A0, A1, A2, A3, A4, A5, frA);
    consume(16 + tl, B0, B1, B2, B3, B4, B5, frB);
    issue(48 + tl,   B0, B1, B2, B3, B4, B5, frB);
    consume(32 + tl, A0, A1, A2, A3, A4, A5, frA);
    consume(48 + tl, B0, B1, B2, B3, B4, B5, frB);
  }
  __syncthreads();

  f32x4 acc[4][4];

  // GEMM: acc[ni][ti] = Wp-layer-L rows [w*64+ni*16 ..] x h-tokens [ti*16 ..]
  // over K=512. W from packed global (coalesced stream), h from LDS. No
  // barriers inside.
  auto gemm = [&](int L) {
    #pragma unroll
    for (int ni = 0; ni < 4; ++ni)
      #pragma unroll
      for (int ti = 0; ti < 4; ++ti) acc[ni][ti] = (f32x4){0.f, 0.f, 0.f, 0.f};
    const u16* Wl = Wp + (size_t)L * 262144 + (w << 15) + (lane << 3);
    #pragma unroll
    for (int kk = 0; kk < 16; ++kk) {
      short8 Wf[4], hf[4];
      #pragma unroll
      for (int ni = 0; ni < 4; ++ni)
        Wf[ni] = *(const short8*)(Wl + (kk << 11) + (ni << 9));
      const int kb = ((kk << 5) + (g << 3)) ^ swz;
      #pragma unroll
      for (int ti = 0; ti < 4; ++ti)
        hf[ti] = *(const short8*)&hbuf[(((ti << 4) + lr) << 9) + kb];
      #pragma unroll
      for (int ni = 0; ni < 4; ++ni)
        #pragma unroll
        for (int ti = 0; ti < 4; ++ti)
          acc[ni][ti] = __builtin_amdgcn_mfma_f32_16x16x32_bf16(Wf[ni], hf[ti], acc[ni][ti], 0, 0, 0);
    }
  };

  // hidden-layer epilogue: h[t][n] = relu(acc + b) (+ h_old), in place
  auto epi_h = [&](const float* __restrict__ bias, bool resid) {
    __syncthreads();                     // all GEMM reads of h done blockwide
    #pragma unroll
    for (int ni = 0; ni < 4; ++ni) {
      const int nb = (w << 6) + (ni << 4) + (g << 2);
      const float4 b4 = *(const float4*)(bias + nb);
      #pragma unroll
      for (int ti = 0; ti < 4; ++ti) {
        const int t = (ti << 4) + lr;
        u16* p = &hbuf[(t << 9) + (nb ^ swz)];
        float v0 = fmaxf(acc[ni][ti][0] + b4.x, 0.f);
        float v1 = fmaxf(acc[ni][ti][1] + b4.y, 0.f);
        float v2 = fmaxf(acc[ni][ti][2] + b4.z, 0.f);
        float v3 = fmaxf(acc[ni][ti][3] + b4.w, 0.f);
        if (resid) {                     // lane-private 8B: safe in-place
          const uint2 r2 = *(const uint2*)p;
          v0 += bf2f((u16)(r2.x & 0xffffu)); v1 += bf2f((u16)(r2.x >> 16));
          v2 += bf2f((u16)(r2.y & 0xffffu)); v3 += bf2f((u16)(r2.y >> 16));
        }
        uint2 o;
        o.x = (uint32_t)f2bf(v0) | ((uint32_t)f2bf(v1) << 16);
        o.y = (uint32_t)f2bf(v2) | ((uint32_t)f2bf(v3) << 16);
        *(uint2*)p = o;
      }
    }
    __syncthreads();
  };

  // output epilogue: coalesced NON-TEMPORAL f32x4 logits stores (streaming
  // 268 MB must not evict hash tables / W from L2)
  auto epi_out = [&](const float* __restrict__ bias, int vb) {
    #pragma unroll
    for (int ni = 0; ni < 4; ++ni) {
      const int nb = (w << 6) + (ni << 4) + (g << 2);
      const float4 b4 = *(const float4*)(bias + nb);
      #pragma unroll
      for (int ti = 0; ti < 4; ++ti) {
        const int t = (ti << 4) + lr;
        f32x4 o;
        o[0] = acc[ni][ti][0] + b4.x;
        o[1] = acc[ni][ti][1] + b4.y;
        o[2] = acc[ni][ti][2] + b4.z;
        o[3] = acc[ni][ti][3] + b4.w;
        __builtin_nontemporal_store(o, (f32x4*)(out + (tok0 + t) * NVOCAB + vb + nb));
      }
    }
  };

  // layer 0: h = relu(W_in f + b_in)
  gemm(0); epi_h(bIn, false);
  // residual blocks: h = relu(W h + b) + h
  gemm(1); epi_h(bMlp,        true);
  gemm(2); epi_h(bMlp + 512,  true);
  gemm(3); epi_h(bMlp + 1024, true);
  // logits (1024 cols = layers 4,5); h read-only now, no barriers needed
  gemm(4); epi_out(bOut,       0);
  gemm(5); epi_out(bOut + 512, 512);
}

extern "C" void kernel_launch(void* const* d_in, const int* in_sizes, int n_in,
                              void* d_out, int out_size, void* d_ws, size_t ws_size,
                              hipStream_t stream) {
  const int*   chars      = (const int*)  d_in[0];
  const float* byte_embed = (const float*)d_in[1];
  const float* hash_tabs  = (const float*)d_in[2];
  const float* w_in       = (const float*)d_in[3];
  const float* b_in       = (const float*)d_in[4];
  const float* mlp_ws     = (const float*)d_in[5];
  const float* mlp_bs     = (const float*)d_in[6];
  const float* w_out      = (const float*)d_in[7];
  const float* b_out      = (const float*)d_in[8];

  // ws: packed weights, 6 layers x 512KB bf16 = 3 MB
  u16* Wp = (u16*)d_ws;

  pack_w<<<dim3(768), dim3(256), 0, stream>>>(w_in, mlp_ws, w_out, Wp);

  fused_all<<<dim3(NTOK / 64), dim3(512), 0, stream>>>(
      chars, byte_embed, hash_tabs, Wp, b_in, mlp_bs, b_out, (float*)d_out);
}